// Round 2
// baseline (337.830 us; speedup 1.0000x reference)
//
#include <hip/hip_runtime.h>
#include <hip/hip_bf16.h>
#include <stdint.h>

// GRU cell, B=32768, IN=256, H=256, CONCAT=512. Fused bf16-MFMA kernel.
// R7 = R6 + slab-pipelined staging (T14 async-STAGE split). The old
// monolithic stage (16 float4 loads + cvt + ds_write, then __syncthreads)
// serialized ~10us of HBM time in front of the K-loop with the MFMA pipe
// idle. Now main-loop group g consumes LDS slab g (k in [64g,64g+64)), so
// staging is folded into the loop: phase p issues global loads for slab
// p+2 (held in regs), runs group p's MFMAs, then converts+writes slab p+1
// and does a raw lgkmcnt(0)+s_barrier. vmcnt is never drained at the
// phase barrier, so stage loads stay in flight under the MFMA block.
// __launch_bounds__(512,4) pins VGPR<=128 to protect 2 blocks/CU.
// (Resubmit: previous round died on container acquisition, not the kernel.)

typedef float  f32x4  __attribute__((ext_vector_type(4)));
typedef __bf16 bf16x8 __attribute__((ext_vector_type(8)));
typedef short  s16x8  __attribute__((ext_vector_type(8)));

#define B_TOT   32768
#define MT      64
#define WRZ_ELEMS (512*512)
#define WG_ELEMS  (256*512)

__device__ __forceinline__ unsigned short f2b(float f) {
    union { float f; unsigned int u; } v; v.f = f;
    unsigned int r = (v.u + 0x7FFFu + ((v.u >> 16) & 1u)) >> 16;  // RNE
    return (unsigned short)r;
}
__device__ __forceinline__ float b2f(unsigned short b) {
    union { unsigned int u; float f; } v; v.u = ((unsigned int)b) << 16;
    return v.f;
}
__device__ __forceinline__ ushort2 pk2(float a, float b) {   // v_cvt_pk_bf16_f32
    __hip_bfloat162 t = __float22bfloat162_rn(make_float2(a, b));
    union { __hip_bfloat162 h; ushort2 u; } c; c.h = t; return c.u;
}
__device__ __forceinline__ float sigmoid_f(float x) {
    return 1.0f / (1.0f + __expf(-x));
}
__device__ __forceinline__ float tanh_f(float x) {
    return 1.0f - 2.0f / (__expf(2.0f * x) + 1.0f);
}

// bf16 LDS tile 64x512 (64 KB), XOR-swizzled at 16B (8-elem) granularity.
__device__ __forceinline__ int lds_idx(int row, int col) {
    return row * 512 + ((((col >> 3) ^ (row & 7)) << 3) | (col & 7));
}

// 8 fp32 -> 8 bf16 -> one 16B LDS write (stage slab stash).
__device__ __forceinline__ void stash8(unsigned short* dst, float4 a, float4 b) {
    union { ushort2 u2[4]; s16x8 v; } pk;
    pk.u2[0] = pk2(a.x, a.y); pk.u2[1] = pk2(a.z, a.w);
    pk.u2[2] = pk2(b.x, b.y); pk.u2[3] = pk2(b.z, b.w);
    *reinterpret_cast<s16x8*>(dst) = pk.v;
}

// ---------------------------------------------------------------------------
// Prep (unchanged): fp32 -> bf16 ks-major per-wave fragment pages.
// wrz page (wave w): [ks 0..15][jn 0..3][512]; jn 0,1 r-cols, jn 2,3 z-cols.
// wg  page (wave w): [ks 0..15][j 0..1][512]; k<256 whx, k>=256 whh.
// ---------------------------------------------------------------------------
__global__ void prep_weights(const float* __restrict__ wr,
                             const float* __restrict__ wz,
                             const float* __restrict__ whh,
                             const float* __restrict__ whx,
                             unsigned short* __restrict__ wrz,
                             unsigned short* __restrict__ wg) {
    const int b = blockIdx.x;
    const int t = threadIdx.x;
    union { s16x8 v; unsigned short u[8]; } tmp;

    if (b < 128) {                       // wrz: block = (w, ks)
        int w = b >> 4, ks = b & 15;
        int jn = t >> 6, l = t & 63;
        int kbase = ks * 32 + ((l >> 4) << 3);
        int n = 32 * w + ((jn & 1) << 4) + (l & 15);
        const float* src = (jn < 2) ? wr : wz;
        #pragma unroll
        for (int jj = 0; jj < 8; ++jj)
            tmp.u[jj] = f2b(src[(kbase + jj) * 256 + n]);
        *reinterpret_cast<s16x8*>(wrz + (size_t)w * 32768 + ks * 2048 + t * 8) = tmp.v;
    } else {                             // wg: block = (w, ks-pair)
        int b2 = b - 128;
        int w = b2 >> 3, ksp = b2 & 7;
        int ksl = t >> 7, j = (t >> 6) & 1, l = t & 63;
        int ks = ksp * 2 + ksl;
        int kbase = ks * 32 + ((l >> 4) << 3);
        int n = 32 * w + (j << 4) + (l & 15);
        #pragma unroll
        for (int jj = 0; jj < 8; ++jj) {
            int k = kbase + jj;
            tmp.u[jj] = f2b((k < 256) ? whx[k * 256 + n] : whh[(k - 256) * 256 + n]);
        }
        *reinterpret_cast<s16x8*>(wg + (size_t)w * 16384 + ksp * 2048 + t * 8) = tmp.v;
    }
}

// ---------------------------------------------------------------------------
// Fused GRU: 512 threads (8 waves), 64 rows/block, grid 512.
// Wave w owns r/z/g cols [32w,32w+32). Slab-pipelined stage + 8 MFMA phases.
// Gates: a=sigmoid(r+br)*h -> x-region; h stashed in r-acc.
// Tail: 4 groups of 2 kt. Epilogue: h + z*(tanh(g+bh)-h).
// ---------------------------------------------------------------------------
__global__ __launch_bounds__(512, 4)
void gru_fused(const float* __restrict__ x, const float* __restrict__ h,
               const unsigned short* __restrict__ wrz,
               const unsigned short* __restrict__ wg,
               const float* __restrict__ br, const float* __restrict__ bz,
               const float* __restrict__ bh, float* __restrict__ out) {
    __shared__ unsigned short xcA[64 * 512];   // 64 KB

    const int tid  = threadIdx.x;
    const int lane = tid & 63;
    const int wv   = tid >> 6;          // wave 0..7
    const int m0   = lane & 15;
    const int q    = lane >> 4;
    const int rowBase = blockIdx.x * MT;

    float brv[2], bzv[2], bhv[2];
    #pragma unroll
    for (int j = 0; j < 2; ++j) {
        int col = 32 * wv + j * 16 + m0;
        brv[j] = br[col]; bzv[j] = bz[col]; bhv[j] = bh[col];
    }

    // ---- Slab staging geometry: slab s = 64 rows x 64 k (k in [64s,64s+64)).
    // Thread t stages row (t>>3), float cols [ (t&7)*8 .. +8 ) of each slab:
    // 2 float4 global loads -> 4 pk2 -> one 16B swizzled LDS write.
    const int srow  = tid >> 3;
    const int scol8 = (tid & 7) << 3;
    const float* xrow = x + (size_t)(rowBase + srow) * 256 + scol8;
    const float* hrow = h + (size_t)(rowBase + srow) * 256 + scol8;

    const unsigned short* wrzP = wrz + (size_t)wv * 32768;
    const unsigned short* wgP  = wg  + (size_t)wv * 16384;

    // ---- Preamble: issue slab 0,1 loads; preload B group 0; write slab 0.
    float4 Sa[2], Sb[2];
    {
        const float4* p0 = reinterpret_cast<const float4*>(xrow);        // slab 0
        Sa[0] = p0[0]; Sb[0] = p0[1];
        const float4* p1 = reinterpret_cast<const float4*>(xrow + 64);   // slab 1
        Sa[1] = p1[0]; Sb[1] = p1[1];
    }

    s16x8 Bb[2][12];
    #pragma unroll
    for (int k2 = 0; k2 < 2; ++k2) {
        #pragma unroll
        for (int jn = 0; jn < 4; ++jn)
            Bb[0][k2 * 6 + jn] = *reinterpret_cast<const s16x8*>(
                wrzP + k2 * 2048 + jn * 512 + lane * 8);
        #pragma unroll
        for (int j = 0; j < 2; ++j)
            Bb[0][k2 * 6 + 4 + j] = *reinterpret_cast<const s16x8*>(
                wgP + k2 * 1024 + j * 512 + lane * 8);
    }

    stash8(&xcA[lds_idx(srow, scol8)], Sa[0], Sb[0]);   // slab 0
    asm volatile("s_waitcnt lgkmcnt(0)" ::: "memory");
    __builtin_amdgcn_sched_barrier(0);
    __builtin_amdgcn_s_barrier();
    __builtin_amdgcn_sched_barrier(0);

    f32x4 rz[4][4];     // jn 0,1 = r; jn 2,3 = z
    f32x4 gac[2][4];
    #pragma unroll
    for (int jn = 0; jn < 4; ++jn)
        #pragma unroll
        for (int mt = 0; mt < 4; ++mt)
            rz[jn][mt] = (f32x4){0.f, 0.f, 0.f, 0.f};
    #pragma unroll
    for (int j = 0; j < 2; ++j)
        #pragma unroll
        for (int mt = 0; mt < 4; ++mt)
            gac[j][mt] = (f32x4){0.f, 0.f, 0.f, 0.f};

    // ---- Main loop: 8 phases. Phase p: issue slab p+2 loads, prefetch B
    // group p+1, MFMA group p (reads slab p), write slab p+1, raw barrier
    // (lgkmcnt only -- stage/B loads stay in flight across the barrier).
    #pragma unroll
    for (int grp = 0; grp < 8; ++grp) {
        const int cur = grp & 1, nxt = cur ^ 1;
        // Stage loads: slab grp+2 -> reg buffer (grp&1)
        if (grp < 6) {
            const int s = grp + 2;
            const float4* p = reinterpret_cast<const float4*>(
                (s < 4) ? (xrow + 64 * s) : (hrow + 64 * (s - 4)));
            Sa[grp & 1] = p[0]; Sb[grp & 1] = p[1];
        }
        // Prefetch next group's B fragments
        if (grp < 7) {
            int gn = grp + 1;
            #pragma unroll
            for (int k2 = 0; k2 < 2; ++k2) {
                int ks = gn * 2 + k2;
                #pragma unroll
                for (int jn = 0; jn < 4; ++jn)
                    Bb[nxt][k2 * 6 + jn] = *reinterpret_cast<const s16x8*>(
                        wrzP + ks * 2048 + jn * 512 + lane * 8);
                if (gn < 4) {
                    #pragma unroll
                    for (int j = 0; j < 2; ++j)
                        Bb[nxt][k2 * 6 + 4 + j] = *reinterpret_cast<const s16x8*>(
                            wgP + ks * 1024 + j * 512 + lane * 8);
                }
            }
        }
        __builtin_amdgcn_sched_barrier(0);   // loads stay above, MFMAs below
        #pragma unroll
        for (int k2 = 0; k2 < 2; ++k2) {
            int ks = grp * 2 + k2;
            bf16x8 afr[4];
            #pragma unroll
            for (int mt = 0; mt < 4; ++mt) {
                int row = mt * 16 + m0;
                int idx = row * 512 + ((((ks << 2) | q) ^ (row & 7)) << 3);
                afr[mt] = __builtin_bit_cast(bf16x8,
                    *reinterpret_cast<const s16x8*>(&xcA[idx]));
            }
            #pragma unroll
            for (int jn = 0; jn < 4; ++jn) {
                bf16x8 bf = __builtin_bit_cast(bf16x8, Bb[cur][k2 * 6 + jn]);
                #pragma unroll
                for (int mt = 0; mt < 4; ++mt)
                    rz[jn][mt] = __builtin_amdgcn_mfma_f32_16x16x32_bf16(
                        afr[mt], bf, rz[jn][mt], 0, 0, 0);
            }
            if (grp < 4) {
                #pragma unroll
                for (int j = 0; j < 2; ++j) {
                    bf16x8 bf = __builtin_bit_cast(bf16x8, Bb[cur][k2 * 6 + 4 + j]);
                    #pragma unroll
                    for (int mt = 0; mt < 4; ++mt)
                        gac[j][mt] = __builtin_amdgcn_mfma_f32_16x16x32_bf16(
                            afr[mt], bf, gac[j][mt], 0, 0, 0);
                }
            }
        }
        __builtin_amdgcn_sched_barrier(0);   // keep slab write below MFMAs
        // Write slab grp+1 (loaded last phase) and phase-barrier.
        if (grp < 7) {
            const int sb = (grp + 1) & 1;
            stash8(&xcA[lds_idx(srow, 64 * (grp + 1) + scol8)], Sa[sb], Sb[sb]);
            asm volatile("s_waitcnt lgkmcnt(0)" ::: "memory");
            __builtin_amdgcn_sched_barrier(0);
            __builtin_amdgcn_s_barrier();
            __builtin_amdgcn_sched_barrier(0);
        }
    }
    __syncthreads();   // all LDS A-reads done before x-region overwrite

    // ---- Preload tail group 0 (whh pages 8,9) — gates VALU hides latency
    s16x8 Tb[2][4];
    #pragma unroll
    for (int k2 = 0; k2 < 2; ++k2)
        #pragma unroll
        for (int j = 0; j < 2; ++j)
            Tb[0][k2 * 2 + j] = *reinterpret_cast<const s16x8*>(
                wgP + (8 + k2) * 1024 + j * 512 + lane * 8);

    // ---- Gates: a = sigmoid(r+br)*h -> LDS x-region; stash h in r-acc
    #pragma unroll
    for (int j = 0; j < 2; ++j) {
        int col = 32 * wv + j * 16 + m0;
        #pragma unroll
        for (int mt = 0; mt < 4; ++mt) {
            #pragma unroll
            for (int rg = 0; rg < 4; ++rg) {
                int row = mt * 16 + q * 4 + rg;
                float hval = b2f(xcA[lds_idx(row, 256 + col)]);
                float rs = sigmoid_f(rz[j][mt][rg] + brv[j]);
                xcA[lds_idx(row, col)] = f2b(rs * hval);
                rz[j][mt][rg] = hval;
            }
        }
    }
    __syncthreads();   // a visible to all waves

    // ---- Tail: g += a @ whh, 4 groups x 2 kt, double-buffered + fenced
    #pragma unroll
    for (int tg = 0; tg < 4; ++tg) {
        const int cur = tg & 1, nxt = cur ^ 1;
        if (tg < 3) {
            #pragma unroll
            for (int k2 = 0; k2 < 2; ++k2)
                #pragma unroll
                for (int j = 0; j < 2; ++j)
                    Tb[nxt][k2 * 2 + j] = *reinterpret_cast<const s16x8*>(
                        wgP + (10 + tg * 2 + k2) * 1024 + j * 512 + lane * 8);
        }
        __builtin_amdgcn_sched_barrier(0);
        #pragma unroll
        for (int k2 = 0; k2 < 2; ++k2) {
            int kt = tg * 2 + k2;
            bf16x8 afr[4];
            #pragma unroll
            for (int mt = 0; mt < 4; ++mt) {
                int row = mt * 16 + m0;
                int idx = row * 512 + ((((kt << 2) | q) ^ (row & 7)) << 3);
                afr[mt] = __builtin_bit_cast(bf16x8,
                    *reinterpret_cast<const s16x8*>(&xcA[idx]));
            }
            #pragma unroll
            for (int j = 0; j < 2; ++j) {
                bf16x8 bf = __builtin_bit_cast(bf16x8, Tb[cur][k2 * 2 + j]);
                #pragma unroll
                for (int mt = 0; mt < 4; ++mt)
                    gac[j][mt] = __builtin_amdgcn_mfma_f32_16x16x32_bf16(
                        afr[mt], bf, gac[j][mt], 0, 0, 0);
            }
        }
    }

    // ---- Epilogue: h_out = h + z*(tanh(g+bh) - h)
    #pragma unroll
    for (int j = 0; j < 2; ++j) {
        int col = 32 * wv + j * 16 + m0;
        #pragma unroll
        for (int mt = 0; mt < 4; ++mt) {
            #pragma unroll
            for (int rg = 0; rg < 4; ++rg) {
                int row = mt * 16 + q * 4 + rg;
                float zs = sigmoid_f(rz[2 + j][mt][rg] + bzv[j]);
                float gv = tanh_f(gac[j][mt][rg] + bhv[j]);
                float hval = rz[j][mt][rg];
                out[(size_t)(rowBase + row) * 256 + col] = hval + zs * (gv - hval);
            }
        }
    }
}

extern "C" void kernel_launch(void* const* d_in, const int* in_sizes, int n_in,
                              void* d_out, int out_size, void* d_ws, size_t ws_size,
                              hipStream_t stream) {
    const float* x   = (const float*)d_in[0];
    const float* h   = (const float*)d_in[1];
    const float* wr  = (const float*)d_in[2];
    const float* wz  = (const float*)d_in[3];
    const float* whh = (const float*)d_in[4];
    const float* whx = (const float*)d_in[5];
    const float* br  = (const float*)d_in[6];
    const float* bz  = (const float*)d_in[7];
    const float* bh  = (const float*)d_in[8];
    float* out = (float*)d_out;

    unsigned short* wrz = (unsigned short*)d_ws;       // 512 KB
    unsigned short* wg  = wrz + WRZ_ELEMS;             // 256 KB

    prep_weights<<<192, 256, 0, stream>>>(wr, wz, whh, whx, wrz, wg);
    gru_fused<<<B_TOT / MT, 512, 0, stream>>>(x, h, wrz, wg, br, bz, bh, out);
}

// Round 3
// 148.929 us; speedup vs baseline: 2.2684x; 2.2684x over previous
//
#include <hip/hip_runtime.h>
#include <hip/hip_bf16.h>
#include <stdint.h>

// GRU cell, B=32768, IN=256, H=256, CONCAT=512. Fused bf16-MFMA kernel.
// R9 = R7 slab pipeline with __launch_bounds__(512,2) restored.
// R8 post-mortem: (512,4) demanded total regs <= 128/lane, but the kernel
// needs ~220 (96 AGPR acc + 96 VGPR B-dbuf + stage/addr). Allocator
// spilled to scratch: VGPR_Count 64, WRITE_SIZE 33->522 GB, hbm_bytes x11,
// 252us. VGPR_Count is ARCH-only; R6's 124 sat beside ~96 AGPRs, i.e. this
// kernel runs 1 block/CU (2 waves/SIMD) -- "protect 2 blocks/CU" was wrong.
// Slab pipeline (unchanged from R7): main-loop group g consumes LDS slab g
// (k in [64g,64g+64)); phase p issues global loads for slab p+2 (regs),
// runs group p's MFMAs, converts+writes slab p+1, raw lgkmcnt(0)+s_barrier.
// vmcnt never drained at the phase barrier -> stage loads fly under MFMAs.

typedef float  f32x4  __attribute__((ext_vector_type(4)));
typedef __bf16 bf16x8 __attribute__((ext_vector_type(8)));
typedef short  s16x8  __attribute__((ext_vector_type(8)));

#define B_TOT   32768
#define MT      64
#define WRZ_ELEMS (512*512)
#define WG_ELEMS  (256*512)

__device__ __forceinline__ unsigned short f2b(float f) {
    union { float f; unsigned int u; } v; v.f = f;
    unsigned int r = (v.u + 0x7FFFu + ((v.u >> 16) & 1u)) >> 16;  // RNE
    return (unsigned short)r;
}
__device__ __forceinline__ float b2f(unsigned short b) {
    union { unsigned int u; float f; } v; v.u = ((unsigned int)b) << 16;
    return v.f;
}
__device__ __forceinline__ ushort2 pk2(float a, float b) {   // v_cvt_pk_bf16_f32
    __hip_bfloat162 t = __float22bfloat162_rn(make_float2(a, b));
    union { __hip_bfloat162 h; ushort2 u; } c; c.h = t; return c.u;
}
__device__ __forceinline__ float sigmoid_f(float x) {
    return 1.0f / (1.0f + __expf(-x));
}
__device__ __forceinline__ float tanh_f(float x) {
    return 1.0f - 2.0f / (__expf(2.0f * x) + 1.0f);
}

// bf16 LDS tile 64x512 (64 KB), XOR-swizzled at 16B (8-elem) granularity.
__device__ __forceinline__ int lds_idx(int row, int col) {
    return row * 512 + ((((col >> 3) ^ (row & 7)) << 3) | (col & 7));
}

// 8 fp32 -> 8 bf16 -> one 16B LDS write (stage slab stash).
__device__ __forceinline__ void stash8(unsigned short* dst, float4 a, float4 b) {
    union { ushort2 u2[4]; s16x8 v; } pk;
    pk.u2[0] = pk2(a.x, a.y); pk.u2[1] = pk2(a.z, a.w);
    pk.u2[2] = pk2(b.x, b.y); pk.u2[3] = pk2(b.z, b.w);
    *reinterpret_cast<s16x8*>(dst) = pk.v;
}

// ---------------------------------------------------------------------------
// Prep (unchanged): fp32 -> bf16 ks-major per-wave fragment pages.
// wrz page (wave w): [ks 0..15][jn 0..3][512]; jn 0,1 r-cols, jn 2,3 z-cols.
// wg  page (wave w): [ks 0..15][j 0..1][512]; k<256 whx, k>=256 whh.
// ---------------------------------------------------------------------------
__global__ void prep_weights(const float* __restrict__ wr,
                             const float* __restrict__ wz,
                             const float* __restrict__ whh,
                             const float* __restrict__ whx,
                             unsigned short* __restrict__ wrz,
                             unsigned short* __restrict__ wg) {
    const int b = blockIdx.x;
    const int t = threadIdx.x;
    union { s16x8 v; unsigned short u[8]; } tmp;

    if (b < 128) {                       // wrz: block = (w, ks)
        int w = b >> 4, ks = b & 15;
        int jn = t >> 6, l = t & 63;
        int kbase = ks * 32 + ((l >> 4) << 3);
        int n = 32 * w + ((jn & 1) << 4) + (l & 15);
        const float* src = (jn < 2) ? wr : wz;
        #pragma unroll
        for (int jj = 0; jj < 8; ++jj)
            tmp.u[jj] = f2b(src[(kbase + jj) * 256 + n]);
        *reinterpret_cast<s16x8*>(wrz + (size_t)w * 32768 + ks * 2048 + t * 8) = tmp.v;
    } else {                             // wg: block = (w, ks-pair)
        int b2 = b - 128;
        int w = b2 >> 3, ksp = b2 & 7;
        int ksl = t >> 7, j = (t >> 6) & 1, l = t & 63;
        int ks = ksp * 2 + ksl;
        int kbase = ks * 32 + ((l >> 4) << 3);
        int n = 32 * w + (j << 4) + (l & 15);
        #pragma unroll
        for (int jj = 0; jj < 8; ++jj) {
            int k = kbase + jj;
            tmp.u[jj] = f2b((k < 256) ? whx[k * 256 + n] : whh[(k - 256) * 256 + n]);
        }
        *reinterpret_cast<s16x8*>(wg + (size_t)w * 16384 + ksp * 2048 + t * 8) = tmp.v;
    }
}

// ---------------------------------------------------------------------------
// Fused GRU: 512 threads (8 waves), 64 rows/block, grid 512.
// Wave w owns r/z/g cols [32w,32w+32). Slab-pipelined stage + 8 MFMA phases.
// Gates: a=sigmoid(r+br)*h -> x-region; h stashed in r-acc.
// Tail: 4 groups of 2 kt. Epilogue: h + z*(tanh(g+bh)-h).
// ---------------------------------------------------------------------------
__global__ __launch_bounds__(512, 2)
void gru_fused(const float* __restrict__ x, const float* __restrict__ h,
               const unsigned short* __restrict__ wrz,
               const unsigned short* __restrict__ wg,
               const float* __restrict__ br, const float* __restrict__ bz,
               const float* __restrict__ bh, float* __restrict__ out) {
    __shared__ unsigned short xcA[64 * 512];   // 64 KB

    const int tid  = threadIdx.x;
    const int lane = tid & 63;
    const int wv   = tid >> 6;          // wave 0..7
    const int m0   = lane & 15;
    const int q    = lane >> 4;
    const int rowBase = blockIdx.x * MT;

    float brv[2], bzv[2], bhv[2];
    #pragma unroll
    for (int j = 0; j < 2; ++j) {
        int col = 32 * wv + j * 16 + m0;
        brv[j] = br[col]; bzv[j] = bz[col]; bhv[j] = bh[col];
    }

    // ---- Slab staging geometry: slab s = 64 rows x 64 k (k in [64s,64s+64)).
    // Thread t stages row (t>>3), float cols [ (t&7)*8 .. +8 ) of each slab:
    // 2 float4 global loads -> 4 pk2 -> one 16B swizzled LDS write.
    const int srow  = tid >> 3;
    const int scol8 = (tid & 7) << 3;
    const float* xrow = x + (size_t)(rowBase + srow) * 256 + scol8;
    const float* hrow = h + (size_t)(rowBase + srow) * 256 + scol8;

    const unsigned short* wrzP = wrz + (size_t)wv * 32768;
    const unsigned short* wgP  = wg  + (size_t)wv * 16384;

    // ---- Preamble: issue slab 0,1 loads; preload B group 0; write slab 0.
    float4 Sa[2], Sb[2];
    {
        const float4* p0 = reinterpret_cast<const float4*>(xrow);        // slab 0
        Sa[0] = p0[0]; Sb[0] = p0[1];
        const float4* p1 = reinterpret_cast<const float4*>(xrow + 64);   // slab 1
        Sa[1] = p1[0]; Sb[1] = p1[1];
    }

    s16x8 Bb[2][12];
    #pragma unroll
    for (int k2 = 0; k2 < 2; ++k2) {
        #pragma unroll
        for (int jn = 0; jn < 4; ++jn)
            Bb[0][k2 * 6 + jn] = *reinterpret_cast<const s16x8*>(
                wrzP + k2 * 2048 + jn * 512 + lane * 8);
        #pragma unroll
        for (int j = 0; j < 2; ++j)
            Bb[0][k2 * 6 + 4 + j] = *reinterpret_cast<const s16x8*>(
                wgP + k2 * 1024 + j * 512 + lane * 8);
    }

    stash8(&xcA[lds_idx(srow, scol8)], Sa[0], Sb[0]);   // slab 0
    asm volatile("s_waitcnt lgkmcnt(0)" ::: "memory");
    __builtin_amdgcn_sched_barrier(0);
    __builtin_amdgcn_s_barrier();
    __builtin_amdgcn_sched_barrier(0);

    f32x4 rz[4][4];     // jn 0,1 = r; jn 2,3 = z
    f32x4 gac[2][4];
    #pragma unroll
    for (int jn = 0; jn < 4; ++jn)
        #pragma unroll
        for (int mt = 0; mt < 4; ++mt)
            rz[jn][mt] = (f32x4){0.f, 0.f, 0.f, 0.f};
    #pragma unroll
    for (int j = 0; j < 2; ++j)
        #pragma unroll
        for (int mt = 0; mt < 4; ++mt)
            gac[j][mt] = (f32x4){0.f, 0.f, 0.f, 0.f};

    // ---- Main loop: 8 phases. Phase p: issue slab p+2 loads, prefetch B
    // group p+1, MFMA group p (reads slab p), write slab p+1, raw barrier
    // (lgkmcnt only -- stage/B loads stay in flight across the barrier).
    #pragma unroll
    for (int grp = 0; grp < 8; ++grp) {
        const int cur = grp & 1, nxt = cur ^ 1;
        // Stage loads: slab grp+2 -> reg buffer (grp&1)
        if (grp < 6) {
            const int s = grp + 2;
            const float4* p = reinterpret_cast<const float4*>(
                (s < 4) ? (xrow + 64 * s) : (hrow + 64 * (s - 4)));
            Sa[grp & 1] = p[0]; Sb[grp & 1] = p[1];
        }
        // Prefetch next group's B fragments
        if (grp < 7) {
            int gn = grp + 1;
            #pragma unroll
            for (int k2 = 0; k2 < 2; ++k2) {
                int ks = gn * 2 + k2;
                #pragma unroll
                for (int jn = 0; jn < 4; ++jn)
                    Bb[nxt][k2 * 6 + jn] = *reinterpret_cast<const s16x8*>(
                        wrzP + ks * 2048 + jn * 512 + lane * 8);
                if (gn < 4) {
                    #pragma unroll
                    for (int j = 0; j < 2; ++j)
                        Bb[nxt][k2 * 6 + 4 + j] = *reinterpret_cast<const s16x8*>(
                            wgP + ks * 1024 + j * 512 + lane * 8);
                }
            }
        }
        __builtin_amdgcn_sched_barrier(0);   // loads stay above, MFMAs below
        #pragma unroll
        for (int k2 = 0; k2 < 2; ++k2) {
            int ks = grp * 2 + k2;
            bf16x8 afr[4];
            #pragma unroll
            for (int mt = 0; mt < 4; ++mt) {
                int row = mt * 16 + m0;
                int idx = row * 512 + ((((ks << 2) | q) ^ (row & 7)) << 3);
                afr[mt] = __builtin_bit_cast(bf16x8,
                    *reinterpret_cast<const s16x8*>(&xcA[idx]));
            }
            #pragma unroll
            for (int jn = 0; jn < 4; ++jn) {
                bf16x8 bf = __builtin_bit_cast(bf16x8, Bb[cur][k2 * 6 + jn]);
                #pragma unroll
                for (int mt = 0; mt < 4; ++mt)
                    rz[jn][mt] = __builtin_amdgcn_mfma_f32_16x16x32_bf16(
                        afr[mt], bf, rz[jn][mt], 0, 0, 0);
            }
            if (grp < 4) {
                #pragma unroll
                for (int j = 0; j < 2; ++j) {
                    bf16x8 bf = __builtin_bit_cast(bf16x8, Bb[cur][k2 * 6 + 4 + j]);
                    #pragma unroll
                    for (int mt = 0; mt < 4; ++mt)
                        gac[j][mt] = __builtin_amdgcn_mfma_f32_16x16x32_bf16(
                            afr[mt], bf, gac[j][mt], 0, 0, 0);
                }
            }
        }
        __builtin_amdgcn_sched_barrier(0);   // keep slab write below MFMAs
        // Write slab grp+1 (loaded last phase) and phase-barrier.
        if (grp < 7) {
            const int sb = (grp + 1) & 1;
            stash8(&xcA[lds_idx(srow, 64 * (grp + 1) + scol8)], Sa[sb], Sb[sb]);
            asm volatile("s_waitcnt lgkmcnt(0)" ::: "memory");
            __builtin_amdgcn_sched_barrier(0);
            __builtin_amdgcn_s_barrier();
            __builtin_amdgcn_sched_barrier(0);
        }
    }
    __syncthreads();   // all LDS A-reads done before x-region overwrite

    // ---- Preload tail group 0 (whh pages 8,9) — gates VALU hides latency
    s16x8 Tb[2][4];
    #pragma unroll
    for (int k2 = 0; k2 < 2; ++k2)
        #pragma unroll
        for (int j = 0; j < 2; ++j)
            Tb[0][k2 * 2 + j] = *reinterpret_cast<const s16x8*>(
                wgP + (8 + k2) * 1024 + j * 512 + lane * 8);

    // ---- Gates: a = sigmoid(r+br)*h -> LDS x-region; stash h in r-acc
    #pragma unroll
    for (int j = 0; j < 2; ++j) {
        int col = 32 * wv + j * 16 + m0;
        #pragma unroll
        for (int mt = 0; mt < 4; ++mt) {
            #pragma unroll
            for (int rg = 0; rg < 4; ++rg) {
                int row = mt * 16 + q * 4 + rg;
                float hval = b2f(xcA[lds_idx(row, 256 + col)]);
                float rs = sigmoid_f(rz[j][mt][rg] + brv[j]);
                xcA[lds_idx(row, col)] = f2b(rs * hval);
                rz[j][mt][rg] = hval;
            }
        }
    }
    __syncthreads();   // a visible to all waves

    // ---- Tail: g += a @ whh, 4 groups x 2 kt, double-buffered + fenced
    #pragma unroll
    for (int tg = 0; tg < 4; ++tg) {
        const int cur = tg & 1, nxt = cur ^ 1;
        if (tg < 3) {
            #pragma unroll
            for (int k2 = 0; k2 < 2; ++k2)
                #pragma unroll
                for (int j = 0; j < 2; ++j)
                    Tb[nxt][k2 * 2 + j] = *reinterpret_cast<const s16x8*>(
                        wgP + (10 + tg * 2 + k2) * 1024 + j * 512 + lane * 8);
        }
        __builtin_amdgcn_sched_barrier(0);
        #pragma unroll
        for (int k2 = 0; k2 < 2; ++k2) {
            int kt = tg * 2 + k2;
            bf16x8 afr[4];
            #pragma unroll
            for (int mt = 0; mt < 4; ++mt) {
                int row = mt * 16 + m0;
                int idx = row * 512 + ((((kt << 2) | q) ^ (row & 7)) << 3);
                afr[mt] = __builtin_bit_cast(bf16x8,
                    *reinterpret_cast<const s16x8*>(&xcA[idx]));
            }
            #pragma unroll
            for (int j = 0; j < 2; ++j) {
                bf16x8 bf = __builtin_bit_cast(bf16x8, Tb[cur][k2 * 2 + j]);
                #pragma unroll
                for (int mt = 0; mt < 4; ++mt)
                    gac[j][mt] = __builtin_amdgcn_mfma_f32_16x16x32_bf16(
                        afr[mt], bf, gac[j][mt], 0, 0, 0);
            }
        }
    }

    // ---- Epilogue: h_out = h + z*(tanh(g+bh) - h)
    #pragma unroll
    for (int j = 0; j < 2; ++j) {
        int col = 32 * wv + j * 16 + m0;
        #pragma unroll
        for (int mt = 0; mt < 4; ++mt) {
            #pragma unroll
            for (int rg = 0; rg < 4; ++rg) {
                int row = mt * 16 + q * 4 + rg;
                float zs = sigmoid_f(rz[2 + j][mt][rg] + bzv[j]);
                float gv = tanh_f(gac[j][mt][rg] + bhv[j]);
                float hval = rz[j][mt][rg];
                out[(size_t)(rowBase + row) * 256 + col] = hval + zs * (gv - hval);
            }
        }
    }
}

extern "C" void kernel_launch(void* const* d_in, const int* in_sizes, int n_in,
                              void* d_out, int out_size, void* d_ws, size_t ws_size,
                              hipStream_t stream) {
    const float* x   = (const float*)d_in[0];
    const float* h   = (const float*)d_in[1];
    const float* wr  = (const float*)d_in[2];
    const float* wz  = (const float*)d_in[3];
    const float* whh = (const float*)d_in[4];
    const float* whx = (const float*)d_in[5];
    const float* br  = (const float*)d_in[6];
    const float* bz  = (const float*)d_in[7];
    const float* bh  = (const float*)d_in[8];
    float* out = (float*)d_out;

    unsigned short* wrz = (unsigned short*)d_ws;       // 512 KB
    unsigned short* wg  = wrz + WRZ_ELEMS;             // 256 KB

    prep_weights<<<192, 256, 0, stream>>>(wr, wz, whh, whx, wrz, wg);
    gru_fused<<<B_TOT / MT, 512, 0, stream>>>(x, h, wrz, wg, br, bz, bh, out);
}